// Round 1
// baseline (201.085 us; speedup 1.0000x reference)
//
#include <hip/hip_runtime.h>

#define N_NODES 100000
#define N_EDGES 1600000
#define D 64
#define N_BBOX 4096
#define CAP 64       // per-node slot capacity; deg ~ Poisson(16), P(>=64) ~ 1e-20
#define NBITW 3136   // words for N_NODES bits, padded
#define SLICE 12500  // N_NODES / 8 XCD slices
#define NBLK_A 6250  // N_EDGES / 256 exactly
#define SEGCAP 96    // unfiltered Binom(256,1/8): mean 32, 96 = +12 sigma
#define NTILE1 (N_NODES / 16)  // 6250
#define NTILE2 (N_BBOX / 16)   // 256

typedef short bf16x8 __attribute__((ext_vector_type(8)));
typedef float f32x4 __attribute__((ext_vector_type(4)));

__device__ __forceinline__ int bperm(int srclane, int v) {
  return __builtin_amdgcn_ds_bpermute(srclane << 2, v);
}
__device__ __forceinline__ float lrelu(float v) {
  return fmaxf(v, 0.01f * v);  // neg_slope 0.01 > 0
}
__device__ __forceinline__ bool testbit(const unsigned* bits, int i) {
  return (bits[i >> 5] >> (i & 31)) & 1u;
}
__device__ __forceinline__ short f2bf(float f) {  // RNE fp32 -> bf16
  unsigned u = __float_as_uint(f);
  u += 0x7FFFu + ((u >> 16) & 1u);
  return (short)(u >> 16);
}

// ---- fused: xprep (x -> bf16) + bbox marking + cnt zeroing ----
__global__ __launch_bounds__(256) void prep_kernel(const float4* __restrict__ x4,
                                                   bf16x8* __restrict__ xb,
                                                   const int* __restrict__ bbox,
                                                   unsigned* __restrict__ is_bbox_bits,
                                                   unsigned* __restrict__ needed_bits,
                                                   int* __restrict__ cnt) {
  const int i = blockIdx.x * 256 + threadIdx.x;
  if (i < N_NODES) cnt[i] = 0;
  if (i < N_NODES * 8) {  // one 8-elem chunk per thread
    const float4 a = x4[i * 2], b = x4[i * 2 + 1];
    bf16x8 r;
    r[0] = f2bf(a.x); r[1] = f2bf(a.y); r[2] = f2bf(a.z); r[3] = f2bf(a.w);
    r[4] = f2bf(b.x); r[5] = f2bf(b.y); r[6] = f2bf(b.z); r[7] = f2bf(b.w);
    xb[i] = r;
  } else {
    const int t = i - N_NODES * 8;
    if (t < N_BBOX) {
      const int n = bbox[t];
      const unsigned m = 1u << (n & 31);
      atomicOr(&is_bbox_bits[n >> 5], m);
      atomicOr(&needed_bits[n >> 5], m);
    }
  }
}

// ---- fused edge scan: mark_needed + unfiltered block-segment binning ----
__global__ __launch_bounds__(256) void scan_kernel(const int* __restrict__ src,
                                                   const int* __restrict__ dst,
                                                   const unsigned* __restrict__ is_bbox_bits,
                                                   unsigned* __restrict__ needed_bits,
                                                   int* __restrict__ qcnt,
                                                   int* __restrict__ qseg) {
  __shared__ int lcnt[8];
  __shared__ int lbuf[8 * SEGCAP];
  const int t = threadIdx.x;
  const int lane = t & 63;
  const int e = blockIdx.x * 256 + t;  // exact: NBLK_A*256 == N_EDGES
  if (t < 8) lcnt[t] = 0;
  __syncthreads();

  const int d = dst[e];
  const int s = src[e];
  if (testbit(is_bbox_bits, d)) {  // ~4% of lanes; L1-hit bitmask
    atomicOr(&needed_bits[s >> 5], 1u << (s & 31));
  }
  const int q = d / SLICE;
  const int pv = s | ((d - q * SLICE) << 17);
#pragma unroll
  for (int qq = 0; qq < 8; qq++) {  // all lanes active: exact grid, no returns
    const unsigned long long mask = __ballot(q == qq);
    if (!mask) continue;
    const int nq = __popcll(mask);
    const int leader = (int)__builtin_ctzll(mask);  // wave-uniform
    int base = 0;
    if (lane == leader) base = atomicAdd(&lcnt[qq], nq);
    base = __builtin_amdgcn_readlane(base, leader);
    if (q == qq) {
      const int p = base + __popcll(mask & ((1ull << lane) - 1ull));
      if (p < SEGCAP) lbuf[qq * SEGCAP + p] = pv;
    }
  }
  __syncthreads();

  const size_t segbase = (size_t)blockIdx.x * 8;
  if (t < 8) qcnt[segbase + t] = (lcnt[t] > SEGCAP) ? SEGCAP : lcnt[t];
  for (int i = t; i < 8 * SEGCAP; i += 256) {
    const int q2 = i / SEGCAP, p2 = i - q2 * SEGCAP;
    if (p2 < lcnt[q2]) qseg[(segbase + q2) * SEGCAP + p2] = lbuf[i];
  }
}

// ---- fill pass B: per-slice scatter from compacted segments + needed filter ----
__global__ __launch_bounds__(256) void scatterB_kernel(const int* __restrict__ qcnt,
                                                       const int* __restrict__ qseg,
                                                       const unsigned* __restrict__ needed_bits,
                                                       int* __restrict__ cnt,
                                                       int* __restrict__ slots) {
  const int sl = blockIdx.x & 7;
  const int bidx = blockIdx.x >> 3;
  const int nblk = gridDim.x >> 3;
  const int base_node = sl * SLICE;
  const int sub = threadIdx.x >> 4;  // 16 segments handled per iteration
  const int pp = threadIdx.x & 15;

  for (int b0 = bidx * 16; b0 < NBLK_A; b0 += nblk * 16) {
    const int b = b0 + sub;
    if (b >= NBLK_A) continue;
    const int n = qcnt[(size_t)b * 8 + sl];
    const int* seg = qseg + ((size_t)b * 8 + sl) * SEGCAP;
    for (int p = pp; p < n; p += 16) {
      const int pv = seg[p];
      const int d = base_node + (pv >> 17);
      if (!testbit(needed_bits, d)) continue;  // L1-hit filter (~50% discard)
      const int pos = atomicAdd(&cnt[d], 1);
      if (pos < CAP) slots[(size_t)d * CAP + pos] = pv & 0x1FFFF;
    }
  }
}

// ---- wave-cooperative gather-sum of bf16 rows listed in slots[node*CAP..] ----
// On exit: accf[i] of lane (g=0,c) holds element c*8+i of the row-sum,
// replicated across all 8 groups.
__device__ __forceinline__ void gather_rows(const uint4* __restrict__ rows,
                                            const int* __restrict__ slots,
                                            int node, int n, int lane,
                                            float accf[8]) {
  const int g = lane >> 3, c = lane & 7;
  const int myslot = (lane < n) ? slots[(size_t)node * CAP + lane] : 0;
#pragma unroll
  for (int i = 0; i < 8; i++) accf[i] = 0.f;
  for (int e0 = 0; e0 < n; e0 += 64) {
    int idx[8], s[8];
    uint4 v[8];
#pragma unroll
    for (int u = 0; u < 8; u++) {
      idx[u] = e0 + u * 8 + g;
      s[u] = bperm(idx[u], myslot);
    }
#pragma unroll
    for (int u = 0; u < 8; u++) {
      v[u] = make_uint4(0u, 0u, 0u, 0u);
      if (idx[u] < n) v[u] = rows[(size_t)s[u] * 8 + c];
    }
#pragma unroll
    for (int u = 0; u < 8; u++) {
      accf[0] += __uint_as_float(v[u].x << 16);
      accf[1] += __uint_as_float(v[u].x & 0xFFFF0000u);
      accf[2] += __uint_as_float(v[u].y << 16);
      accf[3] += __uint_as_float(v[u].y & 0xFFFF0000u);
      accf[4] += __uint_as_float(v[u].z << 16);
      accf[5] += __uint_as_float(v[u].z & 0xFFFF0000u);
      accf[6] += __uint_as_float(v[u].w << 16);
      accf[7] += __uint_as_float(v[u].w & 0xFFFF0000u);
    }
  }
#pragma unroll
  for (int off = 8; off < 64; off <<= 1)
#pragma unroll
    for (int i = 0; i < 8; i++) accf[i] += __shfl_xor(accf[i], off);
}

// ---- fused layer-1: gather agg -> LDS A-tile -> MFMA -> hb (needed rows) ----
// mfma_f32_16x16x32_bf16: A[m=lane&15][k=quad*8+i], B[k][n=lane&15],
// C col=lane&15 row=quad*4+reg. 4 waves: wave wid gathers rows 4wid..4wid+3
// and computes output column-quadrant nt=wid. LDS rows padded to 72 shorts
// (144 B) -> 16-lane column reads land on 2-way bank aliasing only (free).
__global__ __launch_bounds__(256) void gd1_kernel(
    const uint4* __restrict__ xb4, const short* __restrict__ xb,
    const unsigned* __restrict__ needed_bits, const int* __restrict__ cnt,
    const int* __restrict__ slots, const float* __restrict__ W1rel,
    const float* __restrict__ b1, const float* __restrict__ W1root,
    short* __restrict__ hb) {
  __shared__ __align__(16) short aggt[16][72];
  const int t = threadIdx.x;
  const int lane = t & 63;
  const int wid = t >> 6;          // 0..3 = wave id = nt quadrant
  const int cn = lane & 15, quad = lane >> 4;

  bf16x8 brel[2], broot[2];
#pragma unroll
  for (int kh = 0; kh < 2; kh++)
#pragma unroll
    for (int i = 0; i < 8; i++) {
      const int k = kh * 32 + quad * 8 + i;
      brel[kh][i] = f2bf(W1rel[k * D + wid * 16 + cn]);
      broot[kh][i] = f2bf(W1root[k * D + wid * 16 + cn]);
    }
  const float bj = b1[wid * 16 + cn];

  for (int tile = blockIdx.x; tile < NTILE1; tile += gridDim.x) {
    const int node0 = tile * 16;
    // gather phase: non-needed nodes have cnt==0 -> zero row for free
#pragma unroll
    for (int r4 = 0; r4 < 4; r4++) {
      const int row = wid * 4 + r4;
      const int node = node0 + row;
      int n = cnt[node];
      n = (n > CAP) ? CAP : n;
      if (n == 0) {
        if (lane < 8) {
          bf16x8 z = {0, 0, 0, 0, 0, 0, 0, 0};
          *(bf16x8*)(&aggt[row][lane * 8]) = z;
        }
        continue;
      }
      float accf[8];
      gather_rows(xb4, slots, node, n, lane, accf);
      if (lane < 8) {
        bf16x8 r;
#pragma unroll
        for (int i = 0; i < 8; i++) r[i] = f2bf(accf[i]);
        *(bf16x8*)(&aggt[row][lane * 8]) = r;
      }
    }
    __syncthreads();
    // MFMA phase
    const int mrow = node0 + cn;
    const bool ndrow = testbit(needed_bits, mrow);
    f32x4 acc = {};
#pragma unroll
    for (int kh = 0; kh < 2; kh++) {
      const bf16x8 a_agg = *(const bf16x8*)(&aggt[cn][kh * 32 + quad * 8]);
      bf16x8 a_x = {0, 0, 0, 0, 0, 0, 0, 0};
      if (ndrow)
        a_x = *(const bf16x8*)(xb + (size_t)mrow * D + kh * 32 + quad * 8);
      acc = __builtin_amdgcn_mfma_f32_16x16x32_bf16(a_agg, brel[kh], acc, 0, 0, 0);
      acc = __builtin_amdgcn_mfma_f32_16x16x32_bf16(a_x, broot[kh], acc, 0, 0, 0);
    }
#pragma unroll
    for (int r = 0; r < 4; r++) {
      const int row = quad * 4 + r;
      if (testbit(needed_bits, node0 + row))
        hb[(size_t)(node0 + row) * D + wid * 16 + cn] = f2bf(lrelu(acc[r] + bj));
    }
    __syncthreads();  // protect aggt before next tile's gather
  }
}

// ---- fused layer-2: gather agg(h) for 16 bbox nodes -> LDS -> MFMA -> out ----
__global__ __launch_bounds__(256) void gd2_kernel(
    const uint4* __restrict__ hb4, const short* __restrict__ hb,
    const int* __restrict__ cnt, const int* __restrict__ slots,
    const int* __restrict__ bbox, const float* __restrict__ W2rel,
    const float* __restrict__ b2, const float* __restrict__ W2root,
    float* __restrict__ out) {
  __shared__ __align__(16) short aggt[16][72];
  __shared__ int nodes_s[16];
  const int t = threadIdx.x;
  const int lane = t & 63;
  const int wid = t >> 6;
  const int cn = lane & 15, quad = lane >> 4;
  const int t0 = blockIdx.x * 16;  // grid = NTILE2 exactly

  if (t < 16) nodes_s[t] = bbox[t0 + t];

  bf16x8 brel[2], broot[2];
#pragma unroll
  for (int kh = 0; kh < 2; kh++)
#pragma unroll
    for (int i = 0; i < 8; i++) {
      const int k = kh * 32 + quad * 8 + i;
      brel[kh][i] = f2bf(W2rel[k * D + wid * 16 + cn]);
      broot[kh][i] = f2bf(W2root[k * D + wid * 16 + cn]);
    }
  const float bj = b2[wid * 16 + cn];
  __syncthreads();

#pragma unroll
  for (int r4 = 0; r4 < 4; r4++) {
    const int row = wid * 4 + r4;
    const int node = nodes_s[row];
    int n = cnt[node];
    n = (n > CAP) ? CAP : n;
    if (n == 0) {
      if (lane < 8) {
        bf16x8 z = {0, 0, 0, 0, 0, 0, 0, 0};
        *(bf16x8*)(&aggt[row][lane * 8]) = z;
      }
      continue;
    }
    float accf[8];
    gather_rows(hb4, slots, node, n, lane, accf);
    if (lane < 8) {
      bf16x8 r;
#pragma unroll
      for (int i = 0; i < 8; i++) r[i] = f2bf(accf[i]);
      *(bf16x8*)(&aggt[row][lane * 8]) = r;
    }
  }
  __syncthreads();

  const int rnode = nodes_s[cn];  // root row for A[m=cn]
  f32x4 acc = {};
#pragma unroll
  for (int kh = 0; kh < 2; kh++) {
    const bf16x8 a_agg = *(const bf16x8*)(&aggt[cn][kh * 32 + quad * 8]);
    const bf16x8 a_h = *(const bf16x8*)(hb + (size_t)rnode * D + kh * 32 + quad * 8);
    acc = __builtin_amdgcn_mfma_f32_16x16x32_bf16(a_agg, brel[kh], acc, 0, 0, 0);
    acc = __builtin_amdgcn_mfma_f32_16x16x32_bf16(a_h, broot[kh], acc, 0, 0, 0);
  }
#pragma unroll
  for (int r = 0; r < 4; r++) {
    const int row = quad * 4 + r;
    out[(size_t)(t0 + row) * D + wid * 16 + cn] = lrelu(acc[r] + bj);
  }
}

// ---------------- launch ----------------

extern "C" void kernel_launch(void* const* d_in, const int* in_sizes, int n_in,
                              void* d_out, int out_size, void* d_ws, size_t ws_size,
                              hipStream_t stream) {
  const float* x = (const float*)d_in[0];
  const int* ei = (const int*)d_in[1];
  const int* src = ei;
  const int* dst = ei + N_EDGES;
  const int* bbox = (const int*)d_in[2];
  const float* W1rel = (const float*)d_in[3];
  const float* b1 = (const float*)d_in[4];
  const float* W1root = (const float*)d_in[5];
  const float* W2rel = (const float*)d_in[6];
  const float* b2 = (const float*)d_in[7];
  const float* W2root = (const float*)d_in[8];
  float* out = (float*)d_out;

  char* ws = (char*)d_ws;
  size_t off = 0;
  auto alloc = [&](size_t bytes) -> char* {
    char* p = ws + off;
    off = (off + bytes + 511) & ~(size_t)511;
    return p;
  };
  // contiguous zero region: just the two bitmasks (25 KB); cnt zeroed in prep
  unsigned* is_bbox_bits = (unsigned*)alloc(NBITW * sizeof(unsigned));
  unsigned* needed_bits = (unsigned*)alloc(NBITW * sizeof(unsigned));
  char* zero_end = ws + off;
  int* cnt = (int*)alloc(N_NODES * sizeof(int));
  int* qcnt = (int*)alloc((size_t)NBLK_A * 8 * sizeof(int));              // 200 KB
  int* qseg = (int*)alloc((size_t)NBLK_A * 8 * SEGCAP * sizeof(int));     // 19.2 MB
  int* slots = (int*)alloc((size_t)N_NODES * CAP * sizeof(int));          // 25.6 MB
  short* xb = (short*)alloc((size_t)N_NODES * D * sizeof(short));         // 12.8 MB
  short* hb = (short*)alloc((size_t)N_NODES * D * sizeof(short));         // 12.8 MB

  hipMemsetAsync(is_bbox_bits, 0, (size_t)(zero_end - (char*)is_bbox_bits), stream);
  prep_kernel<<<(N_NODES * 8 + N_BBOX + 255) / 256, 256, 0, stream>>>(
      (const float4*)x, (bf16x8*)xb, bbox, is_bbox_bits, needed_bits, cnt);
  scan_kernel<<<NBLK_A, 256, 0, stream>>>(src, dst, is_bbox_bits, needed_bits,
                                          qcnt, qseg);
  scatterB_kernel<<<2048, 256, 0, stream>>>(qcnt, qseg, needed_bits, cnt, slots);
  gd1_kernel<<<2048, 256, 0, stream>>>((const uint4*)xb, xb, needed_bits, cnt,
                                       slots, W1rel, b1, W1root, hb);
  gd2_kernel<<<NTILE2, 256, 0, stream>>>((const uint4*)hb, hb, cnt, slots, bbox,
                                         W2rel, b2, W2root, out);
}

// Round 3
// 194.733 us; speedup vs baseline: 1.0326x; 1.0326x over previous
//
#include <hip/hip_runtime.h>

#define N_NODES 100000
#define N_EDGES 1600000
#define D 64
#define N_BBOX 4096
#define CAP 64       // per-node slot capacity; deg ~ Poisson(16), P(>=64) ~ 1e-20
#define NBITW 3136   // words for N_NODES bits, padded
#define SLICE 12500  // N_NODES / 8 XCD slices
#define NBLK_A 6250  // N_EDGES / 256 exactly
#define SEGCAP 96    // unfiltered Binom(256,1/8): mean 32, 96 = +12 sigma
#define NTILE1 (N_NODES / 16)  // 6250
#define NTILE2 (N_BBOX / 16)   // 256
#define TPB1 2                 // tiles per gd1 block; ONE barrier per block

typedef short bf16x8 __attribute__((ext_vector_type(8)));
typedef float f32x4 __attribute__((ext_vector_type(4)));

__device__ __forceinline__ int bperm(int srclane, int v) {
  return __builtin_amdgcn_ds_bpermute(srclane << 2, v);
}
__device__ __forceinline__ float lrelu(float v) {
  return fmaxf(v, 0.01f * v);  // neg_slope 0.01 > 0
}
__device__ __forceinline__ bool testbit(const unsigned* bits, int i) {
  return (bits[i >> 5] >> (i & 31)) & 1u;
}
__device__ __forceinline__ short f2bf(float f) {  // RNE fp32 -> bf16
  unsigned u = __float_as_uint(f);
  u += 0x7FFFu + ((u >> 16) & 1u);
  return (short)(u >> 16);
}

// ---- fused: xprep (x -> bf16) + bbox marking + cnt zeroing + W frag pack ----
// Weight fragment table (fragment-major bf16): for layer l, mat m (0=rel,1=root),
// kh, quad, col, i: wf[l*8192 + m*4096 + kh*2048 + quad*512 + col*8 + i]
//   = bf16(W[k*64 + col]), k = kh*32 + quad*8 + i.
// Each thread's MFMA B-fragment is then ONE contiguous 16B chunk.
__global__ __launch_bounds__(256) void prep_kernel(const float4* __restrict__ x4,
                                                   bf16x8* __restrict__ xb,
                                                   const int* __restrict__ bbox,
                                                   unsigned* __restrict__ is_bbox_bits,
                                                   unsigned* __restrict__ needed_bits,
                                                   int* __restrict__ cnt,
                                                   const float* __restrict__ W1rel,
                                                   const float* __restrict__ W1root,
                                                   const float* __restrict__ W2rel,
                                                   const float* __restrict__ W2root,
                                                   short* __restrict__ wf) {
  const int i = blockIdx.x * 256 + threadIdx.x;
  if (i < N_NODES) cnt[i] = 0;
  if (i < N_NODES * 8) {  // one 8-elem chunk per thread
    const float4 a = x4[i * 2], b = x4[i * 2 + 1];
    bf16x8 r;
    r[0] = f2bf(a.x); r[1] = f2bf(a.y); r[2] = f2bf(a.z); r[3] = f2bf(a.w);
    r[4] = f2bf(b.x); r[5] = f2bf(b.y); r[6] = f2bf(b.z); r[7] = f2bf(b.w);
    xb[i] = r;
  } else {
    const int t = i - N_NODES * 8;
    if (t < N_BBOX) {
      const int n = bbox[t];
      const unsigned m = 1u << (n & 31);
      atomicOr(&is_bbox_bits[n >> 5], m);
      atomicOr(&needed_bits[n >> 5], m);
    } else if (t < N_BBOX + 4 * 4096) {
      const int t2 = t - N_BBOX;          // [0, 16384)
      const int layer = t2 >> 13;          // 0: W1, 1: W2
      const int r = t2 & 8191;
      const int m = r >> 12;               // 0: rel, 1: root
      const int e = r & 4095;              // dest offset within mat
      const int kh = e >> 11, quad = (e >> 9) & 3;
      const int col = (e >> 3) & 63, ii = e & 7;
      const int k = kh * 32 + quad * 8 + ii;
      const float* W = layer ? (m ? W2root : W2rel) : (m ? W1root : W1rel);
      wf[t2] = f2bf(W[k * 64 + col]);
    }
  }
}

// ---- fused edge scan: mark_needed + unfiltered block-segment binning ----
__global__ __launch_bounds__(256) void scan_kernel(const int* __restrict__ src,
                                                   const int* __restrict__ dst,
                                                   const unsigned* __restrict__ is_bbox_bits,
                                                   unsigned* __restrict__ needed_bits,
                                                   int* __restrict__ qcnt,
                                                   int* __restrict__ qseg) {
  __shared__ int lcnt[8];
  __shared__ int lbuf[8 * SEGCAP];
  const int t = threadIdx.x;
  const int lane = t & 63;
  const int e = blockIdx.x * 256 + t;  // exact: NBLK_A*256 == N_EDGES
  if (t < 8) lcnt[t] = 0;
  __syncthreads();

  const int d = dst[e];
  const int s = src[e];
  if (testbit(is_bbox_bits, d)) {  // ~4% of lanes; L1-hit bitmask
    atomicOr(&needed_bits[s >> 5], 1u << (s & 31));
  }
  const int q = d / SLICE;
  const int pv = s | ((d - q * SLICE) << 17);
#pragma unroll
  for (int qq = 0; qq < 8; qq++) {  // all lanes active: exact grid, no returns
    const unsigned long long mask = __ballot(q == qq);
    if (!mask) continue;
    const int nq = __popcll(mask);
    const int leader = (int)__builtin_ctzll(mask);  // wave-uniform
    int base = 0;
    if (lane == leader) base = atomicAdd(&lcnt[qq], nq);
    base = __builtin_amdgcn_readlane(base, leader);
    if (q == qq) {
      const int p = base + __popcll(mask & ((1ull << lane) - 1ull));
      if (p < SEGCAP) lbuf[qq * SEGCAP + p] = pv;
    }
  }
  __syncthreads();

  const size_t segbase = (size_t)blockIdx.x * 8;
  if (t < 8) qcnt[segbase + t] = (lcnt[t] > SEGCAP) ? SEGCAP : lcnt[t];
  for (int i = t; i < 8 * SEGCAP; i += 256) {
    const int q2 = i / SEGCAP, p2 = i - q2 * SEGCAP;
    if (p2 < lcnt[q2]) qseg[(segbase + q2) * SEGCAP + p2] = lbuf[i];
  }
}

// ---- fill pass B: per-slice scatter from compacted segments + needed filter ----
__global__ __launch_bounds__(256) void scatterB_kernel(const int* __restrict__ qcnt,
                                                       const int* __restrict__ qseg,
                                                       const unsigned* __restrict__ needed_bits,
                                                       int* __restrict__ cnt,
                                                       int* __restrict__ slots) {
  const int sl = blockIdx.x & 7;
  const int bidx = blockIdx.x >> 3;
  const int nblk = gridDim.x >> 3;
  const int base_node = sl * SLICE;
  const int sub = threadIdx.x >> 4;  // 16 segments handled per iteration
  const int pp = threadIdx.x & 15;

  for (int b0 = bidx * 16; b0 < NBLK_A; b0 += nblk * 16) {
    const int b = b0 + sub;
    if (b >= NBLK_A) continue;
    const int n = qcnt[(size_t)b * 8 + sl];
    const int* seg = qseg + ((size_t)b * 8 + sl) * SEGCAP;
    for (int p = pp; p < n; p += 16) {
      const int pv = seg[p];
      const int d = base_node + (pv >> 17);
      if (!testbit(needed_bits, d)) continue;  // L1-hit filter (~50% discard)
      const int pos = atomicAdd(&cnt[d], 1);
      if (pos < CAP) slots[(size_t)d * CAP + pos] = pv & 0x1FFFF;
    }
  }
}

// ---- wave-cooperative gather-sum of bf16 rows listed in slots[node*CAP..] ----
// 4-deep load batches; n is wave-uniform so dead sub-batches are skipped with
// UNIFORM branches (deg~16 -> ~2 active sub-batches, not 8). Summation order
// per lane is identical to the old 8-deep version (idx sequence unchanged).
// On exit: accf[i] of lane (g=0,c) holds element c*8+i, replicated across groups.
__device__ __forceinline__ void gather_rows(const uint4* __restrict__ rows,
                                            const int* __restrict__ slots,
                                            int node, int n, int lane,
                                            float accf[8]) {
  const int g = lane >> 3, c = lane & 7;
  const int myslot = (lane < n) ? slots[(size_t)node * CAP + lane] : 0;
#pragma unroll
  for (int i = 0; i < 8; i++) accf[i] = 0.f;
  for (int e0 = 0; e0 < n; e0 += 32) {
    const int rem = n - e0;  // wave-uniform
    int idx[4], s[4];
    uint4 v[4];
#pragma unroll
    for (int u = 0; u < 4; u++)
      if (u * 8 < rem) {
        idx[u] = e0 + u * 8 + g;
        s[u] = bperm(idx[u], myslot);
      }
#pragma unroll
    for (int u = 0; u < 4; u++)
      if (u * 8 < rem) {
        v[u] = make_uint4(0u, 0u, 0u, 0u);
        if (idx[u] < n) v[u] = rows[(size_t)s[u] * 8 + c];
      }
#pragma unroll
    for (int u = 0; u < 4; u++)
      if (u * 8 < rem) {
        accf[0] += __uint_as_float(v[u].x << 16);
        accf[1] += __uint_as_float(v[u].x & 0xFFFF0000u);
        accf[2] += __uint_as_float(v[u].y << 16);
        accf[3] += __uint_as_float(v[u].y & 0xFFFF0000u);
        accf[4] += __uint_as_float(v[u].z << 16);
        accf[5] += __uint_as_float(v[u].z & 0xFFFF0000u);
        accf[6] += __uint_as_float(v[u].w << 16);
        accf[7] += __uint_as_float(v[u].w & 0xFFFF0000u);
      }
  }
#pragma unroll
  for (int off = 8; off < 64; off <<= 1)
#pragma unroll
    for (int i = 0; i < 8; i++) accf[i] += __shfl_xor(accf[i], off);
}

// ---- fused layer-1: gather agg -> LDS A-tiles -> ONE barrier -> MFMA -> hb ----
// TPB1 tiles per block: each wave gathers 4*TPB1 nodes (independent latency
// chains) before the single __syncthreads; then MFMAs all tiles. No barrier
// in any loop. B fragments are single b128 loads from the prepacked wf table.
__global__ __launch_bounds__(256) void gd1_kernel(
    const uint4* __restrict__ xb4, const short* __restrict__ xb,
    const unsigned* __restrict__ needed_bits, const int* __restrict__ cnt,
    const int* __restrict__ slots, const short* __restrict__ wf1,
    const float* __restrict__ b1, short* __restrict__ hb) {
  __shared__ __align__(16) short aggt[TPB1][16][72];
  const int t = threadIdx.x;
  const int lane = t & 63;
  const int wid = t >> 6;  // 0..3 = wave id = nt quadrant
  const int cn = lane & 15, quad = lane >> 4;
  const int col = wid * 16 + cn;

  const bf16x8* wfv = (const bf16x8*)wf1;
  bf16x8 brel[2], broot[2];
#pragma unroll
  for (int kh = 0; kh < 2; kh++) {
    brel[kh] = wfv[(kh * 4 + quad) * 64 + col];
    broot[kh] = wfv[((2 + kh) * 4 + quad) * 64 + col];
  }
  const float bj = b1[col];

  const int tile0 = blockIdx.x * TPB1;
  const int ntt = (NTILE1 - tile0 < TPB1) ? (NTILE1 - tile0) : TPB1;

  for (int tt = 0; tt < ntt; tt++) {
    const int node0 = (tile0 + tt) * 16;
#pragma unroll
    for (int r4 = 0; r4 < 4; r4++) {
      const int row = wid * 4 + r4;
      const int node = node0 + row;
      int n = cnt[node];
      n = (n > CAP) ? CAP : n;
      if (n == 0) {  // non-needed (scatterB-filtered) or deg-0: zero row
        if (lane < 8) {
          bf16x8 z = {0, 0, 0, 0, 0, 0, 0, 0};
          *(bf16x8*)(&aggt[tt][row][lane * 8]) = z;
        }
        continue;
      }
      float accf[8];
      gather_rows(xb4, slots, node, n, lane, accf);
      if (lane < 8) {
        bf16x8 r;
#pragma unroll
        for (int i = 0; i < 8; i++) r[i] = f2bf(accf[i]);
        *(bf16x8*)(&aggt[tt][row][lane * 8]) = r;
      }
    }
  }
  __syncthreads();  // the ONLY barrier

  for (int tt = 0; tt < ntt; tt++) {
    const int node0 = (tile0 + tt) * 16;
    const int mrow = node0 + cn;
    const bool ndrow = testbit(needed_bits, mrow);
    f32x4 acc = {};
#pragma unroll
    for (int kh = 0; kh < 2; kh++) {
      const bf16x8 a_agg = *(const bf16x8*)(&aggt[tt][cn][kh * 32 + quad * 8]);
      bf16x8 a_x = {0, 0, 0, 0, 0, 0, 0, 0};
      if (ndrow)
        a_x = *(const bf16x8*)(xb + (size_t)mrow * D + kh * 32 + quad * 8);
      acc = __builtin_amdgcn_mfma_f32_16x16x32_bf16(a_agg, brel[kh], acc, 0, 0, 0);
      acc = __builtin_amdgcn_mfma_f32_16x16x32_bf16(a_x, broot[kh], acc, 0, 0, 0);
    }
#pragma unroll
    for (int r = 0; r < 4; r++) {
      const int row = quad * 4 + r;
      if (testbit(needed_bits, node0 + row))
        hb[(size_t)(node0 + row) * D + col] = f2bf(lrelu(acc[r] + bj));
    }
  }
}

// ---- fused layer-2: gather agg(h) for 16 bbox nodes -> LDS -> MFMA -> out ----
__global__ __launch_bounds__(256) void gd2_kernel(
    const uint4* __restrict__ hb4, const short* __restrict__ hb,
    const int* __restrict__ cnt, const int* __restrict__ slots,
    const int* __restrict__ bbox, const short* __restrict__ wf2,
    const float* __restrict__ b2, float* __restrict__ out) {
  __shared__ __align__(16) short aggt[16][72];
  __shared__ int nodes_s[16];
  const int t = threadIdx.x;
  const int lane = t & 63;
  const int wid = t >> 6;
  const int cn = lane & 15, quad = lane >> 4;
  const int col = wid * 16 + cn;
  const int t0 = blockIdx.x * 16;  // grid = NTILE2 exactly

  if (t < 16) nodes_s[t] = bbox[t0 + t];

  const bf16x8* wfv = (const bf16x8*)wf2;
  bf16x8 brel[2], broot[2];
#pragma unroll
  for (int kh = 0; kh < 2; kh++) {
    brel[kh] = wfv[(kh * 4 + quad) * 64 + col];
    broot[kh] = wfv[((2 + kh) * 4 + quad) * 64 + col];
  }
  const float bj = b2[col];
  __syncthreads();

#pragma unroll
  for (int r4 = 0; r4 < 4; r4++) {
    const int row = wid * 4 + r4;
    const int node = nodes_s[row];
    int n = cnt[node];
    n = (n > CAP) ? CAP : n;
    if (n == 0) {
      if (lane < 8) {
        bf16x8 z = {0, 0, 0, 0, 0, 0, 0, 0};
        *(bf16x8*)(&aggt[row][lane * 8]) = z;
      }
      continue;
    }
    float accf[8];
    gather_rows(hb4, slots, node, n, lane, accf);
    if (lane < 8) {
      bf16x8 r;
#pragma unroll
      for (int i = 0; i < 8; i++) r[i] = f2bf(accf[i]);
      *(bf16x8*)(&aggt[row][lane * 8]) = r;
    }
  }
  __syncthreads();

  const int rnode = nodes_s[cn];  // root row for A[m=cn]
  f32x4 acc = {};
#pragma unroll
  for (int kh = 0; kh < 2; kh++) {
    const bf16x8 a_agg = *(const bf16x8*)(&aggt[cn][kh * 32 + quad * 8]);
    const bf16x8 a_h = *(const bf16x8*)(hb + (size_t)rnode * D + kh * 32 + quad * 8);
    acc = __builtin_amdgcn_mfma_f32_16x16x32_bf16(a_agg, brel[kh], acc, 0, 0, 0);
    acc = __builtin_amdgcn_mfma_f32_16x16x32_bf16(a_h, broot[kh], acc, 0, 0, 0);
  }
#pragma unroll
  for (int r = 0; r < 4; r++) {
    const int row = quad * 4 + r;
    out[(size_t)(t0 + row) * D + col] = lrelu(acc[r] + bj);
  }
}

// ---------------- launch ----------------

extern "C" void kernel_launch(void* const* d_in, const int* in_sizes, int n_in,
                              void* d_out, int out_size, void* d_ws, size_t ws_size,
                              hipStream_t stream) {
  const float* x = (const float*)d_in[0];
  const int* ei = (const int*)d_in[1];
  const int* src = ei;
  const int* dst = ei + N_EDGES;
  const int* bbox = (const int*)d_in[2];
  const float* W1rel = (const float*)d_in[3];
  const float* b1 = (const float*)d_in[4];
  const float* W1root = (const float*)d_in[5];
  const float* W2rel = (const float*)d_in[6];
  const float* b2 = (const float*)d_in[7];
  const float* W2root = (const float*)d_in[8];
  float* out = (float*)d_out;

  char* ws = (char*)d_ws;
  size_t off = 0;
  auto alloc = [&](size_t bytes) -> char* {
    char* p = ws + off;
    off = (off + bytes + 511) & ~(size_t)511;
    return p;
  };
  // contiguous zero region: just the two bitmasks (25 KB); cnt zeroed in prep
  unsigned* is_bbox_bits = (unsigned*)alloc(NBITW * sizeof(unsigned));
  unsigned* needed_bits = (unsigned*)alloc(NBITW * sizeof(unsigned));
  char* zero_end = ws + off;
  int* cnt = (int*)alloc(N_NODES * sizeof(int));
  int* qcnt = (int*)alloc((size_t)NBLK_A * 8 * sizeof(int));              // 200 KB
  int* qseg = (int*)alloc((size_t)NBLK_A * 8 * SEGCAP * sizeof(int));     // 19.2 MB
  int* slots = (int*)alloc((size_t)N_NODES * CAP * sizeof(int));          // 25.6 MB
  short* xb = (short*)alloc((size_t)N_NODES * D * sizeof(short));         // 12.8 MB
  short* hb = (short*)alloc((size_t)N_NODES * D * sizeof(short));         // 12.8 MB
  short* wf = (short*)alloc((size_t)4 * 4096 * sizeof(short));            // 32 KB

  hipMemsetAsync(is_bbox_bits, 0, (size_t)(zero_end - (char*)is_bbox_bits), stream);
  prep_kernel<<<(N_NODES * 8 + N_BBOX + 4 * 4096 + 255) / 256, 256, 0, stream>>>(
      (const float4*)x, (bf16x8*)xb, bbox, is_bbox_bits, needed_bits, cnt,
      W1rel, W1root, W2rel, W2root, wf);
  scan_kernel<<<NBLK_A, 256, 0, stream>>>(src, dst, is_bbox_bits, needed_bits,
                                          qcnt, qseg);
  scatterB_kernel<<<2048, 256, 0, stream>>>(qcnt, qseg, needed_bits, cnt, slots);
  gd1_kernel<<<(NTILE1 + TPB1 - 1) / TPB1, 256, 0, stream>>>(
      (const uint4*)xb, xb, needed_bits, cnt, slots, wf, b1, hb);
  gd2_kernel<<<NTILE2, 256, 0, stream>>>((const uint4*)hb, hb, cnt, slots, bbox,
                                         wf + 8192, b2, out);
}

// Round 4
// 193.685 us; speedup vs baseline: 1.0382x; 1.0054x over previous
//
#include <hip/hip_runtime.h>

#define N_NODES 100000
#define N_EDGES 1600000
#define D 64
#define N_BBOX 4096
#define CAP 64       // per-node slot capacity; deg ~ Poisson(16), P(>=64) ~ 1e-20
#define NBITW 3136   // words for N_NODES bits, padded
#define SLICE 12500  // N_NODES / 8 XCD slices
#define NBLK_A 6250  // N_EDGES / 256 exactly
#define SEGCAP 96    // unfiltered Binom(256,1/8): mean 32, 96 = +12 sigma
#define NTILE1 (N_NODES / 16)  // 6250
#define NTILE2 (N_BBOX / 16)   // 256
#define TPB1 2                 // tiles per gd1 block; ONE barrier per block

typedef short bf16x8 __attribute__((ext_vector_type(8)));
typedef float f32x4 __attribute__((ext_vector_type(4)));

__device__ __forceinline__ int bperm(int srclane, int v) {
  return __builtin_amdgcn_ds_bpermute(srclane << 2, v);
}
__device__ __forceinline__ float lrelu(float v) {
  return fmaxf(v, 0.01f * v);  // neg_slope 0.01 > 0
}
__device__ __forceinline__ bool testbit(const unsigned* bits, int i) {
  return (bits[i >> 5] >> (i & 31)) & 1u;
}
__device__ __forceinline__ short f2bf(float f) {  // RNE fp32 -> bf16
  unsigned u = __float_as_uint(f);
  u += 0x7FFFu + ((u >> 16) & 1u);
  return (short)(u >> 16);
}
__device__ __forceinline__ void unpack_acc(const uint4 v, float f[8]) {
  f[0] += __uint_as_float(v.x << 16);
  f[1] += __uint_as_float(v.x & 0xFFFF0000u);
  f[2] += __uint_as_float(v.y << 16);
  f[3] += __uint_as_float(v.y & 0xFFFF0000u);
  f[4] += __uint_as_float(v.z << 16);
  f[5] += __uint_as_float(v.z & 0xFFFF0000u);
  f[6] += __uint_as_float(v.w << 16);
  f[7] += __uint_as_float(v.w & 0xFFFF0000u);
}

// ---- fused: xprep (x -> bf16) + bbox marking + cnt zeroing + W frag pack ----
// Weight fragment table (fragment-major bf16): for layer l, mat m (0=rel,1=root),
// kh, quad, col, i: wf[l*8192 + m*4096 + kh*2048 + quad*512 + col*8 + i]
//   = bf16(W[k*64 + col]), k = kh*32 + quad*8 + i.
__global__ __launch_bounds__(256) void prep_kernel(const float4* __restrict__ x4,
                                                   bf16x8* __restrict__ xb,
                                                   const int* __restrict__ bbox,
                                                   unsigned* __restrict__ is_bbox_bits,
                                                   unsigned* __restrict__ needed_bits,
                                                   int* __restrict__ cnt,
                                                   const float* __restrict__ W1rel,
                                                   const float* __restrict__ W1root,
                                                   const float* __restrict__ W2rel,
                                                   const float* __restrict__ W2root,
                                                   short* __restrict__ wf) {
  const int i = blockIdx.x * 256 + threadIdx.x;
  if (i < N_NODES) cnt[i] = 0;
  if (i < N_NODES * 8) {  // one 8-elem chunk per thread
    const float4 a = x4[i * 2], b = x4[i * 2 + 1];
    bf16x8 r;
    r[0] = f2bf(a.x); r[1] = f2bf(a.y); r[2] = f2bf(a.z); r[3] = f2bf(a.w);
    r[4] = f2bf(b.x); r[5] = f2bf(b.y); r[6] = f2bf(b.z); r[7] = f2bf(b.w);
    xb[i] = r;
  } else {
    const int t = i - N_NODES * 8;
    if (t < N_BBOX) {
      const int n = bbox[t];
      const unsigned m = 1u << (n & 31);
      atomicOr(&is_bbox_bits[n >> 5], m);
      atomicOr(&needed_bits[n >> 5], m);
    } else if (t < N_BBOX + 4 * 4096) {
      const int t2 = t - N_BBOX;          // [0, 16384)
      const int layer = t2 >> 13;          // 0: W1, 1: W2
      const int r = t2 & 8191;
      const int m = r >> 12;               // 0: rel, 1: root
      const int e = r & 4095;              // dest offset within mat
      const int kh = e >> 11, quad = (e >> 9) & 3;
      const int col = (e >> 3) & 63, ii = e & 7;
      const int k = kh * 32 + quad * 8 + ii;
      const float* W = layer ? (m ? W2root : W2rel) : (m ? W1root : W1rel);
      wf[t2] = f2bf(W[k * 64 + col]);
    }
  }
}

// ---- fused edge scan: mark_needed + unfiltered block-segment binning ----
__global__ __launch_bounds__(256) void scan_kernel(const int* __restrict__ src,
                                                   const int* __restrict__ dst,
                                                   const unsigned* __restrict__ is_bbox_bits,
                                                   unsigned* __restrict__ needed_bits,
                                                   int* __restrict__ qcnt,
                                                   int* __restrict__ qseg) {
  __shared__ int lcnt[8];
  __shared__ int lbuf[8 * SEGCAP];
  const int t = threadIdx.x;
  const int lane = t & 63;
  const int e = blockIdx.x * 256 + t;  // exact: NBLK_A*256 == N_EDGES
  if (t < 8) lcnt[t] = 0;
  __syncthreads();

  const int d = dst[e];
  const int s = src[e];
  if (testbit(is_bbox_bits, d)) {  // ~4% of lanes; L1-hit bitmask
    atomicOr(&needed_bits[s >> 5], 1u << (s & 31));
  }
  const int q = d / SLICE;
  const int pv = s | ((d - q * SLICE) << 17);
#pragma unroll
  for (int qq = 0; qq < 8; qq++) {  // all lanes active: exact grid, no returns
    const unsigned long long mask = __ballot(q == qq);
    if (!mask) continue;
    const int nq = __popcll(mask);
    const int leader = (int)__builtin_ctzll(mask);  // wave-uniform
    int base = 0;
    if (lane == leader) base = atomicAdd(&lcnt[qq], nq);
    base = __builtin_amdgcn_readlane(base, leader);
    if (q == qq) {
      const int p = base + __popcll(mask & ((1ull << lane) - 1ull));
      if (p < SEGCAP) lbuf[qq * SEGCAP + p] = pv;
    }
  }
  __syncthreads();

  const size_t segbase = (size_t)blockIdx.x * 8;
  if (t < 8) qcnt[segbase + t] = (lcnt[t] > SEGCAP) ? SEGCAP : lcnt[t];
  for (int i = t; i < 8 * SEGCAP; i += 256) {
    const int q2 = i / SEGCAP, p2 = i - q2 * SEGCAP;
    if (p2 < lcnt[q2]) qseg[(segbase + q2) * SEGCAP + p2] = lbuf[i];
  }
}

// ---- fill pass B: per-slice scatter from compacted segments + needed filter ----
__global__ __launch_bounds__(256) void scatterB_kernel(const int* __restrict__ qcnt,
                                                       const int* __restrict__ qseg,
                                                       const unsigned* __restrict__ needed_bits,
                                                       int* __restrict__ cnt,
                                                       int* __restrict__ slots) {
  const int sl = blockIdx.x & 7;
  const int bidx = blockIdx.x >> 3;
  const int nblk = gridDim.x >> 3;
  const int base_node = sl * SLICE;
  const int sub = threadIdx.x >> 4;  // 16 segments handled per iteration
  const int pp = threadIdx.x & 15;

  for (int b0 = bidx * 16; b0 < NBLK_A; b0 += nblk * 16) {
    const int b = b0 + sub;
    if (b >= NBLK_A) continue;
    const int n = qcnt[(size_t)b * 8 + sl];
    const int* seg = qseg + ((size_t)b * 8 + sl) * SEGCAP;
    for (int p = pp; p < n; p += 16) {
      const int pv = seg[p];
      const int d = base_node + (pv >> 17);
      if (!testbit(needed_bits, d)) continue;  // L1-hit filter (~50% discard)
      const int pos = atomicAdd(&cnt[d], 1);
      if (pos < CAP) slots[(size_t)d * CAP + pos] = pv & 0x1FFFF;
    }
  }
}

// ---- dual-pair gather: 4 nodes per wave, two per 32-lane half-pair ----
// Half h (lane>>5) of pair q owns node (A if h==0 else B). Within a half:
// 4 groups (g = (lane&31)>>3) x 8 chunk-lanes (c). Per u-step a half covers
// 4 rows: idx = u*4 + g. ALL bperm+loads for rows 0..31 of all 4 nodes issue
// before the first unpack (-> ~16 dwordx4 in flight vs ~2 in the serial
// version). n is clamped <= CAP by caller. Rare n>32 tail in guarded block.
// On exit (after off=8,16 reduce): f_q[i] of lane (hl<8, c=hl) holds element
// c*8+i of node (q,h)'s neighbor-sum.
__device__ __forceinline__ void gather_pair2(
    const uint4* __restrict__ rows, const int* __restrict__ slots,
    int ndA0, int nA0, int ndB0, int nB0,
    int ndA1, int nA1, int ndB1, int nB1,
    int lane, float f0[8], float f1[8]) {
  const int h = lane >> 5, hl = lane & 31;
  const int g = hl >> 3, c = hl & 7;
  const int nm0 = nA0 > nB0 ? nA0 : nB0;   // wave-uniform
  const int nm1 = nA1 > nB1 ? nA1 : nB1;   // wave-uniform
  const int n0 = h ? nB0 : nA0;
  const int n1 = h ? nB1 : nA1;
  const int nd0 = h ? ndB0 : ndA0;
  const int nd1 = h ? ndB1 : ndA1;
  const int ms0 = (hl < n0) ? slots[(size_t)nd0 * CAP + hl] : 0;
  const int ms1 = (hl < n1) ? slots[(size_t)nd1 * CAP + hl] : 0;
#pragma unroll
  for (int i = 0; i < 8; i++) { f0[i] = 0.f; f1[i] = 0.f; }

  uint4 v0[8], v1[8];
  // issue pass: bperm + predicated load, rows 0..31 of all 4 nodes
#pragma unroll
  for (int u = 0; u < 8; u++) {
    if (u * 4 < nm0) {
      const int s = bperm(h * 32 + u * 4 + g, ms0);
      v0[u] = make_uint4(0u, 0u, 0u, 0u);
      if (u * 4 + g < n0) v0[u] = rows[(size_t)s * 8 + c];
    }
    if (u * 4 < nm1) {
      const int s = bperm(h * 32 + u * 4 + g, ms1);
      v1[u] = make_uint4(0u, 0u, 0u, 0u);
      if (u * 4 + g < n1) v1[u] = rows[(size_t)s * 8 + c];
    }
  }
  // unpack pass
#pragma unroll
  for (int u = 0; u < 8; u++) {
    if (u * 4 < nm0) unpack_acc(v0[u], f0);
    if (u * 4 < nm1) unpack_acc(v1[u], f1);
  }
  // rare tails: rows 32..63 (P(n>32) ~ 3e-5)
  if (nm0 > 32) {
    const int ms2 = (32 + hl < n0) ? slots[(size_t)nd0 * CAP + 32 + hl] : 0;
#pragma unroll
    for (int u = 0; u < 8; u++)
      if (32 + u * 4 < nm0) {
        const int idx = 32 + u * 4 + g;
        const int s = bperm(h * 32 + u * 4 + g, ms2);
        uint4 v = make_uint4(0u, 0u, 0u, 0u);
        if (idx < n0) v = rows[(size_t)s * 8 + c];
        unpack_acc(v, f0);
      }
  }
  if (nm1 > 32) {
    const int ms2 = (32 + hl < n1) ? slots[(size_t)nd1 * CAP + 32 + hl] : 0;
#pragma unroll
    for (int u = 0; u < 8; u++)
      if (32 + u * 4 < nm1) {
        const int idx = 32 + u * 4 + g;
        const int s = bperm(h * 32 + u * 4 + g, ms2);
        uint4 v = make_uint4(0u, 0u, 0u, 0u);
        if (idx < n1) v = rows[(size_t)s * 8 + c];
        unpack_acc(v, f1);
      }
  }
  // reduce within each 32-lane half (groups 0..3)
#pragma unroll
  for (int off = 8; off < 32; off <<= 1)
#pragma unroll
    for (int i = 0; i < 8; i++) {
      f0[i] += __shfl_xor(f0[i], off);
      f1[i] += __shfl_xor(f1[i], off);
    }
}

// ---- fused layer-1: dual-pair gather -> LDS A-tiles -> ONE barrier -> MFMA ----
// Wave wid's 8 nodes (2 tiles x rows wid*4..wid*4+3) processed as 2 group
// calls of 2 pairs each. Weights loaded AFTER the barrier (keeps gather-phase
// VGPR pressure down; wf table is L1-hot).
__global__ __launch_bounds__(256, 4) void gd1_kernel(
    const uint4* __restrict__ xb4, const short* __restrict__ xb,
    const unsigned* __restrict__ needed_bits, const int* __restrict__ cnt,
    const int* __restrict__ slots, const short* __restrict__ wf1,
    const float* __restrict__ b1, short* __restrict__ hb) {
  __shared__ __align__(16) short aggt[TPB1][16][72];
  const int t = threadIdx.x;
  const int lane = t & 63;
  const int wid = t >> 6;  // 0..3 = wave id = nt quadrant
  const int h = lane >> 5, hl = lane & 31;
  const int cn = lane & 15, quad = lane >> 4;
  const int col = wid * 16 + cn;
  const int tile0 = blockIdx.x * TPB1;  // grid*TPB1 == NTILE1 exactly

  int nodes[8], nn[8];
#pragma unroll
  for (int j = 0; j < 8; j++) {  // j = tt*4 + r4
    nodes[j] = (tile0 + (j >> 2)) * 16 + wid * 4 + (j & 3);
    int n = cnt[nodes[j]];
    nn[j] = (n > CAP) ? CAP : n;
  }

#pragma unroll
  for (int tt = 0; tt < TPB1; tt++) {
    float f0[8], f1[8];
    const int j0 = tt * 4;
    gather_pair2(xb4, slots, nodes[j0], nn[j0], nodes[j0 + 1], nn[j0 + 1],
                 nodes[j0 + 2], nn[j0 + 2], nodes[j0 + 3], nn[j0 + 3],
                 lane, f0, f1);
    if (hl < 8) {
      bf16x8 r0, r1;
#pragma unroll
      for (int i = 0; i < 8; i++) { r0[i] = f2bf(f0[i]); r1[i] = f2bf(f1[i]); }
      *(bf16x8*)(&aggt[tt][wid * 4 + h][hl * 8]) = r0;       // pair 0: r4 = h
      *(bf16x8*)(&aggt[tt][wid * 4 + 2 + h][hl * 8]) = r1;   // pair 1: r4 = 2+h
    }
  }
  __syncthreads();  // the ONLY barrier

  const bf16x8* wfv = (const bf16x8*)wf1;
  bf16x8 brel[2], broot[2];
#pragma unroll
  for (int kh = 0; kh < 2; kh++) {
    brel[kh] = wfv[(kh * 4 + quad) * 64 + col];
    broot[kh] = wfv[((2 + kh) * 4 + quad) * 64 + col];
  }
  const float bj = b1[col];

#pragma unroll
  for (int tt = 0; tt < TPB1; tt++) {
    const int node0 = (tile0 + tt) * 16;
    const int mrow = node0 + cn;
    const bool ndrow = testbit(needed_bits, mrow);
    f32x4 acc = {};
#pragma unroll
    for (int kh = 0; kh < 2; kh++) {
      const bf16x8 a_agg = *(const bf16x8*)(&aggt[tt][cn][kh * 32 + quad * 8]);
      bf16x8 a_x = {0, 0, 0, 0, 0, 0, 0, 0};
      if (ndrow)
        a_x = *(const bf16x8*)(xb + (size_t)mrow * D + kh * 32 + quad * 8);
      acc = __builtin_amdgcn_mfma_f32_16x16x32_bf16(a_agg, brel[kh], acc, 0, 0, 0);
      acc = __builtin_amdgcn_mfma_f32_16x16x32_bf16(a_x, broot[kh], acc, 0, 0, 0);
    }
#pragma unroll
    for (int r = 0; r < 4; r++) {
      const int row = quad * 4 + r;
      if (testbit(needed_bits, node0 + row))
        hb[(size_t)(node0 + row) * D + col] = f2bf(lrelu(acc[r] + bj));
    }
  }
}

// ---- fused layer-2: dual-pair gather of h for 16 bbox nodes -> MFMA -> out ----
__global__ __launch_bounds__(256, 4) void gd2_kernel(
    const uint4* __restrict__ hb4, const short* __restrict__ hb,
    const int* __restrict__ cnt, const int* __restrict__ slots,
    const int* __restrict__ bbox, const short* __restrict__ wf2,
    const float* __restrict__ b2, float* __restrict__ out) {
  __shared__ __align__(16) short aggt[16][72];
  __shared__ int nodes_s[16];
  const int t = threadIdx.x;
  const int lane = t & 63;
  const int wid = t >> 6;
  const int h = lane >> 5, hl = lane & 31;
  const int cn = lane & 15, quad = lane >> 4;
  const int col = wid * 16 + cn;
  const int t0 = blockIdx.x * 16;  // grid = NTILE2 exactly

  if (t < 16) nodes_s[t] = bbox[t0 + t];
  __syncthreads();

  int nodes[4], nn[4];
#pragma unroll
  for (int j = 0; j < 4; j++) {
    nodes[j] = nodes_s[wid * 4 + j];
    int n = cnt[nodes[j]];
    nn[j] = (n > CAP) ? CAP : n;
  }
  float f0[8], f1[8];
  gather_pair2(hb4, slots, nodes[0], nn[0], nodes[1], nn[1],
               nodes[2], nn[2], nodes[3], nn[3], lane, f0, f1);
  if (hl < 8) {
    bf16x8 r0, r1;
#pragma unroll
    for (int i = 0; i < 8; i++) { r0[i] = f2bf(f0[i]); r1[i] = f2bf(f1[i]); }
    *(bf16x8*)(&aggt[wid * 4 + h][hl * 8]) = r0;
    *(bf16x8*)(&aggt[wid * 4 + 2 + h][hl * 8]) = r1;
  }
  __syncthreads();

  const bf16x8* wfv = (const bf16x8*)wf2;
  bf16x8 brel[2], broot[2];
#pragma unroll
  for (int kh = 0; kh < 2; kh++) {
    brel[kh] = wfv[(kh * 4 + quad) * 64 + col];
    broot[kh] = wfv[((2 + kh) * 4 + quad) * 64 + col];
  }
  const float bj = b2[col];

  const int rnode = nodes_s[cn];  // root row for A[m=cn]
  f32x4 acc = {};
#pragma unroll
  for (int kh = 0; kh < 2; kh++) {
    const bf16x8 a_agg = *(const bf16x8*)(&aggt[cn][kh * 32 + quad * 8]);
    const bf16x8 a_h = *(const bf16x8*)(hb + (size_t)rnode * D + kh * 32 + quad * 8);
    acc = __builtin_amdgcn_mfma_f32_16x16x32_bf16(a_agg, brel[kh], acc, 0, 0, 0);
    acc = __builtin_amdgcn_mfma_f32_16x16x32_bf16(a_h, broot[kh], acc, 0, 0, 0);
  }
#pragma unroll
  for (int r = 0; r < 4; r++) {
    const int row = quad * 4 + r;
    out[(size_t)(t0 + row) * D + col] = lrelu(acc[r] + bj);
  }
}

// ---------------- launch ----------------

extern "C" void kernel_launch(void* const* d_in, const int* in_sizes, int n_in,
                              void* d_out, int out_size, void* d_ws, size_t ws_size,
                              hipStream_t stream) {
  const float* x = (const float*)d_in[0];
  const int* ei = (const int*)d_in[1];
  const int* src = ei;
  const int* dst = ei + N_EDGES;
  const int* bbox = (const int*)d_in[2];
  const float* W1rel = (const float*)d_in[3];
  const float* b1 = (const float*)d_in[4];
  const float* W1root = (const float*)d_in[5];
  const float* W2rel = (const float*)d_in[6];
  const float* b2 = (const float*)d_in[7];
  const float* W2root = (const float*)d_in[8];
  float* out = (float*)d_out;

  char* ws = (char*)d_ws;
  size_t off = 0;
  auto alloc = [&](size_t bytes) -> char* {
    char* p = ws + off;
    off = (off + bytes + 511) & ~(size_t)511;
    return p;
  };
  // contiguous zero region: just the two bitmasks (25 KB); cnt zeroed in prep
  unsigned* is_bbox_bits = (unsigned*)alloc(NBITW * sizeof(unsigned));
  unsigned* needed_bits = (unsigned*)alloc(NBITW * sizeof(unsigned));
  char* zero_end = ws + off;
  int* cnt = (int*)alloc(N_NODES * sizeof(int));
  int* qcnt = (int*)alloc((size_t)NBLK_A * 8 * sizeof(int));              // 200 KB
  int* qseg = (int*)alloc((size_t)NBLK_A * 8 * SEGCAP * sizeof(int));     // 19.2 MB
  int* slots = (int*)alloc((size_t)N_NODES * CAP * sizeof(int));          // 25.6 MB
  short* xb = (short*)alloc((size_t)N_NODES * D * sizeof(short));         // 12.8 MB
  short* hb = (short*)alloc((size_t)N_NODES * D * sizeof(short));         // 12.8 MB
  short* wf = (short*)alloc((size_t)4 * 4096 * sizeof(short));            // 32 KB

  hipMemsetAsync(is_bbox_bits, 0, (size_t)(zero_end - (char*)is_bbox_bits), stream);
  prep_kernel<<<(N_NODES * 8 + N_BBOX + 4 * 4096 + 255) / 256, 256, 0, stream>>>(
      (const float4*)x, (bf16x8*)xb, bbox, is_bbox_bits, needed_bits, cnt,
      W1rel, W1root, W2rel, W2root, wf);
  scan_kernel<<<NBLK_A, 256, 0, stream>>>(src, dst, is_bbox_bits, needed_bits,
                                          qcnt, qseg);
  scatterB_kernel<<<2048, 256, 0, stream>>>(qcnt, qseg, needed_bits, cnt, slots);
  gd1_kernel<<<NTILE1 / TPB1, 256, 0, stream>>>(
      (const uint4*)xb, xb, needed_bits, cnt, slots, wf, b1, hb);
  gd2_kernel<<<NTILE2, 256, 0, stream>>>((const uint4*)hb, hb, cnt, slots, bbox,
                                         wf + 8192, b2, out);
}